// Round 4
// baseline (44.917 us; speedup 1.0000x reference)
//
#include <hip/hip_runtime.h>
#include <hip/hip_bf16.h>

#define D_IN   256
#define UNITS  128
#define LORA_R 4
#define GRID_GEMM 8192   // 8192 blocks x 16 rows = 131072 rows

typedef __attribute__((ext_vector_type(8))) short short8;
typedef __attribute__((ext_vector_type(4))) float f32x4;

// f32 -> bf16 bits, round-to-nearest-even (prep kernel only; not hot)
static __device__ __forceinline__ unsigned short f2bf(float f) {
    unsigned u = __float_as_uint(f);
    unsigned r = (u + 0x7FFFu + ((u >> 16) & 1u)) >> 16;
    return (unsigned short)r;
}

// async global->LDS, 16B per lane. ldsptr is the WAVE-UNIFORM base;
// HW stores lane l's 16B at base + l*16 (m104/m108).
static __device__ __forceinline__ void gll16(const void* g, void* l) {
    __builtin_amdgcn_global_load_lds(
        (const __attribute__((address_space(1))) unsigned int*)g,
        (__attribute__((address_space(3))) unsigned int*)l,
        16, 0, 0);
}

// Kernel 1: fold LoRA into effective weight/bias.
//   W_eff[k][n] = kernel[k][n] + sum_r A[idx][k][r] * B[idx][r][n]   (bf16)
// stored in MFMA B-fragment order:
//   wfrag[((s*8 + t)*64 + lane)*8 + j],  s=k>>5, t=n>>4,
//   lane = ((k>>3)&3)*16 + (n&15), j = k&7
__global__ void mlora_prep(const float* __restrict__ a_kernel,
                           const float* __restrict__ b_kernel,
                           const float* __restrict__ domain_bias,
                           const float* __restrict__ kernel,
                           const float* __restrict__ bias,
                           const int* __restrict__ dom,
                           unsigned short* __restrict__ wfrag,
                           float* __restrict__ bias_eff) {
    const int idx = dom[0];
    const int tid = blockIdx.x * 256 + threadIdx.x;   // 0..32767
    const int n = tid & (UNITS - 1);
    const int k = tid >> 7;
    const float* __restrict__ A = a_kernel + (size_t)idx * D_IN * LORA_R;
    const float* __restrict__ B = b_kernel + (size_t)idx * LORA_R * UNITS;
    float w = kernel[k * UNITS + n];
#pragma unroll
    for (int r = 0; r < LORA_R; ++r) w += A[k * LORA_R + r] * B[r * UNITS + n];
    const int s = k >> 5, g = (k >> 3) & 3, j = k & 7;
    const int t = n >> 4, lo = n & 15;
    const int lane = g * 16 + lo;
    wfrag[(size_t)((s * 8 + t) * 64 + lane) * 8 + j] = f2bf(w);
    if (tid < UNITS) bias_eff[tid] = bias[tid] + domain_bias[idx * UNITS + tid];
}

// Kernel 2: out = relu(x @ W_eff + bias_eff)
// One 16-row tile per block; no loop, no double-buffer, ONE barrier.
// 256 thr = 4 waves; wave w owns cols [32w, 32w+32) (N-tiles 2w, 2w+1).
// Burst-stage 16 KiB via global_load_lds; 5 blocks/CU so other blocks'
// compute hides this block's load drain (TLP pipelining, m114).
// Per-row source chunks XOR-swizzled by (row&7); reads XOR the same
// pattern (rule #21) -> verified bit-exact in R2/R3.
__global__ __launch_bounds__(256, 5) void mlora_gemm(
    const float* __restrict__ x,
    const unsigned short* __restrict__ wfrag,
    const float* __restrict__ bias_eff,
    float* __restrict__ out) {
    __shared__ float lds[16 * 256];   // 16 KiB
    const int lane = threadIdx.x & 63;
    const int wave = threadIdx.x >> 6;   // 0..3
    const int t0 = wave * 2;             // first N-tile
    const int rlo = lane & 15;
    const int g = lane >> 4;

    // issue register-destined B-fragment loads first: their latency and the
    // x staging latency overlap (both drain at/before the barrier+first use)
    short8 bfrag[8][2];
#pragma unroll
    for (int s = 0; s < 8; ++s) {
#pragma unroll
        for (int tt = 0; tt < 2; ++tt) {
            bfrag[s][tt] = *reinterpret_cast<const short8*>(
                wfrag + (size_t)((s * 8 + t0 + tt) * 64 + lane) * 8);
        }
    }
    const float b0 = bias_eff[t0 * 16 + rlo];
    const float b1 = bias_eff[(t0 + 1) * 16 + rlo];

    // burst-stage the block's 16 rows: wave w loads rows w*4 .. w*4+3,
    // one global_load_lds (1 KiB, source chunk (lane) ^ (row&7)) per row.
    const size_t row0 = (size_t)blockIdx.x * 16;
    const char* gbase = (const char*)x + (row0 + wave * 4) * 1024;
    char* lbase = (char*)lds + (size_t)wave * 4 * 1024;
#pragma unroll
    for (int i = 0; i < 4; ++i) {
        const int rsw = (wave * 4 + i) & 7;
        gll16(gbase + (size_t)i * 1024 + ((lane * 16) ^ (rsw << 4)),
              lbase + (size_t)i * 1024);
    }
    __syncthreads();   // single drain: tile resident

    const int swz = (rlo & 7) << 4;
    const char* lrow = (const char*)lds + (size_t)rlo * 1024;
    f32x4 acc0 = {0.f, 0.f, 0.f, 0.f};
    f32x4 acc1 = {0.f, 0.f, 0.f, 0.f};
#pragma unroll
    for (int s = 0; s < 8; ++s) {
        const int base = s * 128 + g * 32;
        f32x4 u0 = *reinterpret_cast<const f32x4*>(lrow + (base ^ swz));
        f32x4 u1 = *reinterpret_cast<const f32x4*>(lrow + ((base + 16) ^ swz));
        union { short8 s8; __hip_bfloat162 h2[4]; } af;
        af.h2[0] = __float22bfloat162_rn(make_float2(u0[0], u0[1]));
        af.h2[1] = __float22bfloat162_rn(make_float2(u0[2], u0[3]));
        af.h2[2] = __float22bfloat162_rn(make_float2(u1[0], u1[1]));
        af.h2[3] = __float22bfloat162_rn(make_float2(u1[2], u1[3]));
        acc0 = __builtin_amdgcn_mfma_f32_16x16x32_bf16(af.s8, bfrag[s][0], acc0, 0, 0, 0);
        acc1 = __builtin_amdgcn_mfma_f32_16x16x32_bf16(af.s8, bfrag[s][1], acc1, 0, 0, 0);
    }
    // D layout: row = row0 + g*4 + j, col = tile*16 + rlo
    float* op = out + (row0 + g * 4) * UNITS;
#pragma unroll
    for (int j = 0; j < 4; ++j) {
        op[(size_t)j * UNITS + t0 * 16 + rlo]      = fmaxf(acc0[j] + b0, 0.f);
        op[(size_t)j * UNITS + t0 * 16 + 16 + rlo] = fmaxf(acc1[j] + b1, 0.f);
    }
}

extern "C" void kernel_launch(void* const* d_in, const int* in_sizes, int n_in,
                              void* d_out, int out_size, void* d_ws, size_t ws_size,
                              hipStream_t stream) {
    const float* x           = (const float*)d_in[0];
    const int*   dom         = (const int*)d_in[1];
    const float* a_kernel    = (const float*)d_in[2];
    const float* b_kernel    = (const float*)d_in[3];
    const float* domain_bias = (const float*)d_in[4];
    const float* kernel      = (const float*)d_in[5];
    const float* bias        = (const float*)d_in[6];
    float* out = (float*)d_out;

    unsigned short* wfrag = (unsigned short*)d_ws;            // 32768 bf16 = 64 KiB
    float* bias_eff = (float*)((char*)d_ws + 65536);          // 128 f32

    mlora_prep<<<128, 256, 0, stream>>>(a_kernel, b_kernel, domain_bias,
                                        kernel, bias, dom, wfrag, bias_eff);
    mlora_gemm<<<GRID_GEMM, 256, 0, stream>>>(x, wfrag, bias_eff, out);
}

// Round 5
// 40.626 us; speedup vs baseline: 1.1056x; 1.1056x over previous
//
#include <hip/hip_runtime.h>
#include <hip/hip_bf16.h>

#define D_IN   256
#define UNITS  128
#define LORA_R 4
#define ROWS_PER_TILE   16
#define TILES_PER_BLOCK 4      // 64 rows per block
#define GRID_GEMM       2048   // 2048 * 64 = 131072 rows

typedef __attribute__((ext_vector_type(8))) short short8;
typedef __attribute__((ext_vector_type(4))) float f32x4;

// raw barrier WITH compile-time memory ordering (no vmcnt(0) drain, unlike
// __syncthreads) and counted vmcnt waits (T3/T4: loads/stores stay in flight)
#define BARRIER()  asm volatile("s_barrier" ::: "memory")
#define VMCNT(n)   asm volatile("s_waitcnt vmcnt(" #n ")" ::: "memory")

// f32 -> bf16 bits, round-to-nearest-even (prep kernel only; not hot)
static __device__ __forceinline__ unsigned short f2bf(float f) {
    unsigned u = __float_as_uint(f);
    unsigned r = (u + 0x7FFFu + ((u >> 16) & 1u)) >> 16;
    return (unsigned short)r;
}

// async global->LDS, 16B per lane. ldsptr is the WAVE-UNIFORM base;
// HW stores lane l's 16B at base + l*16 (m104/m108).
static __device__ __forceinline__ void gll16(const void* g, void* l) {
    __builtin_amdgcn_global_load_lds(
        (const __attribute__((address_space(1))) unsigned int*)g,
        (__attribute__((address_space(3))) unsigned int*)l,
        16, 0, 0);
}

// Kernel 1: fold LoRA into effective weight/bias.
//   W_eff[k][n] = kernel[k][n] + sum_r A[idx][k][r] * B[idx][r][n]   (bf16)
// stored in MFMA B-fragment order:
//   wfrag[((s*8 + t)*64 + lane)*8 + j],  s=k>>5, t=n>>4,
//   lane = ((k>>3)&3)*16 + (n&15), j = k&7
__global__ void mlora_prep(const float* __restrict__ a_kernel,
                           const float* __restrict__ b_kernel,
                           const float* __restrict__ domain_bias,
                           const float* __restrict__ kernel,
                           const float* __restrict__ bias,
                           const int* __restrict__ dom,
                           unsigned short* __restrict__ wfrag,
                           float* __restrict__ bias_eff) {
    const int idx = dom[0];
    const int tid = blockIdx.x * 256 + threadIdx.x;   // 0..32767
    const int n = tid & (UNITS - 1);
    const int k = tid >> 7;
    const float* __restrict__ A = a_kernel + (size_t)idx * D_IN * LORA_R;
    const float* __restrict__ B = b_kernel + (size_t)idx * LORA_R * UNITS;
    float w = kernel[k * UNITS + n];
#pragma unroll
    for (int r = 0; r < LORA_R; ++r) w += A[k * LORA_R + r] * B[r * UNITS + n];
    const int s = k >> 5, g = (k >> 3) & 3, j = k & 7;
    const int t = n >> 4, lo = n & 15;
    const int lane = g * 16 + lo;
    wfrag[(size_t)((s * 8 + t) * 64 + lane) * 8 + j] = f2bf(w);
    if (tid < UNITS) bias_eff[tid] = bias[tid] + domain_bias[idx * UNITS + tid];
}

// Kernel 2: out = relu(x @ W_eff + bias_eff)
// R3 structure (passing, 41.1us) with ONE change: __syncthreads() replaced
// by raw s_barrier + counted vmcnt, so the tile-t+1 prefetch and tile-t-1
// stores stay in flight across tile boundaries (no vmcnt(0) drain).
// Per-wave program order at the tile-t wait:  [stage_t (4)] stores_{t-1} (8)
// stage_{t+1} (4)  -> vmcnt(12) guarantees stage_t landed (vmcnt(4) at t=0,
// vmcnt(8) at the last tile where no new stage was issued).
__global__ __launch_bounds__(256, 4) void mlora_gemm(
    const float* __restrict__ x,
    const unsigned short* __restrict__ wfrag,
    const float* __restrict__ bias_eff,
    float* __restrict__ out) {
    __shared__ float lds[2][ROWS_PER_TILE * 256];   // 2 x 16 KiB
    const int lane = threadIdx.x & 63;
    const int wave = threadIdx.x >> 6;   // 0..3
    const int t0 = wave * 2;             // first N-tile
    const int rlo = lane & 15;
    const int g = lane >> 4;

    // register-resident B fragments (L2-hot: 64 KiB total, read once/block)
    short8 bfrag[8][2];
#pragma unroll
    for (int s = 0; s < 8; ++s) {
#pragma unroll
        for (int tt = 0; tt < 2; ++tt) {
            bfrag[s][tt] = *reinterpret_cast<const short8*>(
                wfrag + (size_t)((s * 8 + t0 + tt) * 64 + lane) * 8);
        }
    }
    const float b0 = bias_eff[t0 * 16 + rlo];
    const float b1 = bias_eff[(t0 + 1) * 16 + rlo];

    const size_t block_row0 = (size_t)blockIdx.x * (ROWS_PER_TILE * TILES_PER_BLOCK);
    const int swz = (rlo & 7) << 4;

    // stage tile -> lds[buf]: wave w loads tile-rows w*4 .. w*4+3, one
    // global_load_lds (1 KiB, source chunk (lane) ^ (row&7)) per row.
    auto stage = [&](int bufi, int tile) {
        const char* gbase = (const char*)x +
            (block_row0 + (size_t)tile * ROWS_PER_TILE + wave * 4) * 1024;
        char* lbase = (char*)&lds[bufi][0] + (size_t)wave * 4 * 1024;
#pragma unroll
        for (int i = 0; i < 4; ++i) {
            const int rsw = (wave * 4 + i) & 7;
            gll16(gbase + (size_t)i * 1024 + ((lane * 16) ^ (rsw << 4)),
                  lbase + (size_t)i * 1024);
        }
    };

    // verified R3 compute body (swizzled LDS reads, cvt_pk, 16 MFMA, stores)
    auto compute_tile = [&](int bufi, int tile) {
        const size_t r0g = block_row0 + (size_t)tile * ROWS_PER_TILE;
        const char* lrow = (const char*)&lds[bufi][0] + (size_t)rlo * 1024;
        f32x4 acc0 = {0.f, 0.f, 0.f, 0.f};
        f32x4 acc1 = {0.f, 0.f, 0.f, 0.f};
#pragma unroll
        for (int s = 0; s < 8; ++s) {
            const int base = s * 128 + g * 32;
            f32x4 u0 = *reinterpret_cast<const f32x4*>(lrow + (base ^ swz));
            f32x4 u1 = *reinterpret_cast<const f32x4*>(lrow + ((base + 16) ^ swz));
            union { short8 s8; __hip_bfloat162 h2[4]; } af;
            af.h2[0] = __float22bfloat162_rn(make_float2(u0[0], u0[1]));
            af.h2[1] = __float22bfloat162_rn(make_float2(u0[2], u0[3]));
            af.h2[2] = __float22bfloat162_rn(make_float2(u1[0], u1[1]));
            af.h2[3] = __float22bfloat162_rn(make_float2(u1[2], u1[3]));
            acc0 = __builtin_amdgcn_mfma_f32_16x16x32_bf16(af.s8, bfrag[s][0], acc0, 0, 0, 0);
            acc1 = __builtin_amdgcn_mfma_f32_16x16x32_bf16(af.s8, bfrag[s][1], acc1, 0, 0, 0);
        }
        // D layout: row = r0g + g*4 + j, col = tile*16 + rlo
        float* op = out + (r0g + g * 4) * UNITS;
#pragma unroll
        for (int j = 0; j < 4; ++j) {
            op[(size_t)j * UNITS + t0 * 16 + rlo]      = fmaxf(acc0[j] + b0, 0.f);
            op[(size_t)j * UNITS + t0 * 16 + 16 + rlo] = fmaxf(acc1[j] + b1, 0.f);
        }
    };

    stage(0, 0);

    // ---- t = 0 ----
    stage(1, 1);
    VMCNT(4);          // drains bfrag/bias/stage0; stage1 (newest 4) in flight
    BARRIER();         // all waves: tile 0 resident
    compute_tile(0, 0);
    BARRIER();         // all waves done reading buf0 before t=1 overwrites... (t=1 stages buf0? no: t=1 stages tile2->buf0) -- protects buf0 reuse
    // ---- t = 1 ----
    stage(0, 2);
    VMCNT(12);         // newest 12 = stores_t0(8) + stage2(4); stage1 landed
    BARRIER();
    compute_tile(1, 1);
    BARRIER();
    // ---- t = 2 ----
    stage(1, 3);
    VMCNT(12);         // newest 12 = stores_t1(8) + stage3(4); stage2 landed
    BARRIER();
    compute_tile(0, 2);
    BARRIER();
    // ---- t = 3 ----
    VMCNT(8);          // newest 8 = stores_t2; stage3 landed
    BARRIER();
    compute_tile(1, 3);
}

extern "C" void kernel_launch(void* const* d_in, const int* in_sizes, int n_in,
                              void* d_out, int out_size, void* d_ws, size_t ws_size,
                              hipStream_t stream) {
    const float* x           = (const float*)d_in[0];
    const int*   dom         = (const int*)d_in[1];
    const float* a_kernel    = (const float*)d_in[2];
    const float* b_kernel    = (const float*)d_in[3];
    const float* domain_bias = (const float*)d_in[4];
    const float* kernel      = (const float*)d_in[5];
    const float* bias        = (const float*)d_in[6];
    float* out = (float*)d_out;

    unsigned short* wfrag = (unsigned short*)d_ws;            // 32768 bf16 = 64 KiB
    float* bias_eff = (float*)((char*)d_ws + 65536);          // 128 f32

    mlora_prep<<<128, 256, 0, stream>>>(a_kernel, b_kernel, domain_bias,
                                        kernel, bias, dom, wfrag, bias_eff);
    mlora_gemm<<<GRID_GEMM, 256, 0, stream>>>(x, wfrag, bias_eff, out);
}